// Round 5
// baseline (281.103 us; speedup 1.0000x reference)
//
#include <hip/hip_runtime.h>
#include <math.h>

#define NB 4
#define NC 128
#define NH 128
#define NW 128
#define NHW (NH*NW)
#define NCOUT 128

// ws float offsets
#define SY_OFF 0
#define SX_OFF 1179648
#define MK_OFF 2359296
#define WOFF_OFF 3538944    // bf16 wA_off: 64*1152 shorts
#define WMAIN_OFF 3575808   // bf16 main weights, 36 PADDED slabs [128][36] shorts

typedef short short8 __attribute__((ext_vector_type(8)));
typedef float f32x4 __attribute__((ext_vector_type(4)));

__device__ inline short f2bf(float f) {
    unsigned u = __float_as_uint(f);
    u = (u + 0x7FFFu + ((u >> 16) & 1u)) >> 16;   // RNE
    return (short)u;
}
__device__ inline unsigned pack2(float lo, float hi) {
    return ((unsigned)(unsigned short)f2bf(lo)) |
           (((unsigned)(unsigned short)f2bf(hi)) << 16);
}
__device__ inline void gload_lds16(const void* g, void* l) {
    __builtin_amdgcn_global_load_lds(
        (const __attribute__((address_space(1))) unsigned int*)g,
        (__attribute__((address_space(3))) unsigned int*)l, 16, 0, 0);
}

// ---------------------------------------------------------------------------
// wtrans: offset-conv table [cout][k2][cin] (pad 64) +
//         main table: 36 PADDED slabs [(chunk*9+k2)][cout][36] (cols 32..35 = 0)
// ---------------------------------------------------------------------------
__global__ void wtrans_kernel(const float* __restrict__ w_off,
                              const float* __restrict__ weight,
                              float* __restrict__ ws)
{
    int i = blockIdx.x * 256 + threadIdx.x;
    if (i < 64*1152) {
        int cout = i / 1152, rem = i - cout*1152;
        int k2 = rem >> 7, cin = rem & 127;
        float v = (cout < 54) ? w_off[(cout*NC + cin)*9 + k2] : 0.f;
        ((short*)(ws + WOFF_OFF))[i] = f2bf(v);
    } else if (i < 64*1152 + 36*4608) {
        int j = i - 64*1152;
        int s = j / 4608, rem = j - s*4608;
        int row = rem / 36, c = rem - row*36;
        int chunk = s / 9, k2 = s - 9*chunk;
        float v = (c < 32) ? weight[(row*NC + chunk*32 + c)*9 + k2] : 0.f;
        ((short*)(ws + WMAIN_OFF))[j] = f2bf(v);
    }
}

// ---------------------------------------------------------------------------
// offconv: 3x3 conv, 54 ch (pad 64) via MFMA. Block = (b, ho, half-row 64px).
// ---------------------------------------------------------------------------
__global__ __launch_bounds__(256) void offconv_kernel(
    const float* __restrict__ x, const float* __restrict__ b_off,
    float* __restrict__ ws)
{
    __shared__ short xs[3][66][40];
    int bid = blockIdx.x;
    bid = (bid & 7) * 128 + (bid >> 3);     // XCD swizzle (1024 = 8*128)
    const int b   = bid >> 8;
    const int ho  = (bid >> 1) & 127;
    const int wb  = (bid & 1) * 64;
    const int tid = threadIdx.x;
    const int lane = tid & 63;
    const int wid = tid >> 6;
    const int n = lane & 15, g = lane >> 4;
    const int px0 = 16 * wid;
    const short* wA = (const short*)(ws + WOFF_OFF);

    f32x4 acc[4];
#pragma unroll
    for (int rf = 0; rf < 4; ++rf) acc[rf] = (f32x4){0.f,0.f,0.f,0.f};

    for (int c0 = 0; c0 < NC; c0 += 32) {
        __syncthreads();
        for (int e = tid; e < 3*66*4; e += 256) {
            int col = e % 66;
            int t2  = e / 66;
            int cg  = t2 & 3;
            int ky  = t2 >> 2;
            int y    = ho - 1 + ky;
            int gcol = wb + col - 1;
            float v[8];
            if ((unsigned)y < NH && (unsigned)gcol < NW) {
                const float* p = x + ((b*NC + c0 + 8*cg)*NH + y)*NW + gcol;
#pragma unroll
                for (int q = 0; q < 8; ++q) v[q] = p[q*NHW];
            } else {
#pragma unroll
                for (int q = 0; q < 8; ++q) v[q] = 0.f;
            }
            uint4 u = make_uint4(pack2(v[0],v[1]), pack2(v[2],v[3]),
                                 pack2(v[4],v[5]), pack2(v[6],v[7]));
            *(uint4*)&xs[ky][col][8*cg] = u;
        }
        __syncthreads();

#pragma unroll
        for (int k2 = 0; k2 < 9; ++k2) {
            const int ky = k2 / 3, kx = k2 % 3;
            short8 bf = *(const short8*)&xs[ky][px0 + n + kx][8*g];
#pragma unroll
            for (int rf = 0; rf < 4; ++rf) {
                short8 af = *(const short8*)&wA[((16*rf + n)*9 + k2)*128 + c0 + 8*g];
                acc[rf] = __builtin_amdgcn_mfma_f32_16x16x32_bf16(af, bf, acc[rf], 0,0,0);
            }
        }
    }

    const int px = wb + px0 + n;
#pragma unroll
    for (int rf = 0; rf < 4; ++rf) {
#pragma unroll
        for (int r = 0; r < 4; ++r) {
            int cout = 16*rf + 4*g + r;
            if (cout >= 54) continue;
            float v = acc[rf][r] + b_off[cout];
            if (cout < 36) {
                int og = cout / 18, rem = cout - 18*og;
                int k2c = rem >> 1, d = cout & 1;
                float base = d ? (float)(px - 1 + (k2c % 3))
                              : (float)(ho - 1 + (k2c / 3));
                ws[(d ? SX_OFF : SY_OFF) + (((b*2+og)*9 + k2c)*NHW) + ho*NW + px] = v + base;
            } else {
                int cc = cout - 36;
                int og = cc / 9, k2c = cc - 9*og;
                ws[MK_OFF + (((b*2+og)*9 + k2c)*NHW) + ho*NW + px] = 1.f/(1.f+expf(-v));
            }
        }
    }
}

// ---------------------------------------------------------------------------
// deform: block = (b, ho): 128 px x 128 cout, 512 threads = 8 waves.
// cin-chunk outer (L2-resident), k2 inner; 36 iterations.
// T14 split: gathers(it+1) issued BEFORE MFMA(it); FMA/pack/ds_write AFTER.
// Padded weight slabs [128][36] -> conflict-free A-reads.
// ---------------------------------------------------------------------------
__global__ __launch_bounds__(512, 4) void deform_kernel(
    const float* __restrict__ x, const float* __restrict__ ws,
    const float* __restrict__ bias, float* __restrict__ out)
{
    __shared__ int4   pI[9][128];         // 18432 B
    __shared__ float4 pW[9][128];         // 18432 B
    __shared__ short  vals[2][128][40];   // 20480 B
    __shared__ short  wslab[2][4608];     // 18432 B, [128][36] padded rows

    int bid = blockIdx.x;
    bid = (bid & 7) * 64 + (bid >> 3);      // XCD swizzle (512 = 8*64)
    const int b   = bid >> 7;
    const int ho  = bid & 127;
    const int tid = threadIdx.x;
    const int lane = tid & 63;
    const int wid = tid >> 6;               // 0..7
    const int n = lane & 15, g = lane >> 4;
    const int ch  = wid & 1;                // cout half (MFMA role)
    const int pxq = wid >> 1;               // px quarter (MFMA role)
    const int sp  = tid & 127;              // pixel (sampling role)
    const int sub = tid >> 7;               // 8-cin subgroup (sampling role)
    const short* wmn = (const short*)(ws + WMAIN_OFF);
    const char*  xB  = (const char*)(x + (long)b*NC*NHW);

    f32x4 acc[4][2];
#pragma unroll
    for (int rf = 0; rf < 4; ++rf) {
        acc[rf][0] = (f32x4){0.f,0.f,0.f,0.f};
        acc[rf][1] = (f32x4){0.f,0.f,0.f,0.f};
    }

    // slab DMA: 9216 B = 512x16 + 64x16
    auto DMA = [&](int slabIdx, int buf) {
        const short* src = wmn + slabIdx*4608;
        gload_lds16(src + tid*8, &wslab[buf][tid*8]);
        if (tid < 64) gload_lds16(src + 4096 + tid*8, &wslab[buf][4096 + tid*8]);
    };

    // prologue: DMA slab 0
    DMA(0, 0);

#pragma unroll 1
    for (int og = 0; og < 2; ++og) {
        if (og) __syncthreads();
        // ---- build bilinear params for this og
        for (int e = tid; e < 1152; e += 512) {
            const int k2 = e >> 7, px = e & 127;
            const int sidx = (((b*2+og)*9 + k2)*NHW) + ho*NW + px;
            const float sy = ws[SY_OFF + sidx];
            const float sx = ws[SX_OFF + sidx];
            const float m  = ws[MK_OFF + sidx];
            const float y0f = floorf(sy), x0f = floorf(sx);
            const float ly = sy - y0f, lx = sx - x0f;
            const int y0 = (int)y0f, x0i = (int)x0f;
            const int y1 = y0 + 1, x1 = x0i + 1;
            const bool vy0 = (unsigned)y0 < NH, vy1 = (unsigned)y1 < NH;
            const bool vx0 = (unsigned)x0i < NW, vx1 = (unsigned)x1 < NW;
            const int cy0 = min(max(y0,0),NH-1), cy1 = min(max(y1,0),NH-1);
            const int cx0 = min(max(x0i,0),NW-1), cx1 = min(max(x1,0),NW-1);
            pI[k2][px] = make_int4((cy0*NW + cx0)*4, (cy0*NW + cx1)*4,
                                   (cy1*NW + cx0)*4, (cy1*NW + cx1)*4);
            pW[k2][px] = make_float4(
                (vy0 && vx0) ? (1.f-ly)*(1.f-lx)*m : 0.f,
                (vy0 && vx1) ? (1.f-ly)*lx*m       : 0.f,
                (vy1 && vx0) ? ly*(1.f-lx)*m       : 0.f,
                (vy1 && vx1) ? ly*lx*m             : 0.f);
        }
        __syncthreads();

        const int it0 = og*18;

        // prologue sample for it0 (load + finish immediately)
        {
            const int chunk = it0/9, k2n = it0 - 9*chunk;
            const int4  I  = pI[k2n][sp];
            const float4 Wv = pW[k2n][sp];
            const char* xc = xB + (long)(chunk*32 + sub*8) * (NHW*4);
            float a0[8], a1[8], a2[8], a3[8];
#pragma unroll
            for (int q = 0; q < 8; ++q) {
                const char* p = xc + q*(NHW*4);
                a0[q] = *(const float*)(p + I.x);
                a1[q] = *(const float*)(p + I.y);
                a2[q] = *(const float*)(p + I.z);
                a3[q] = *(const float*)(p + I.w);
            }
            uint4 u; unsigned* up = (unsigned*)&u;
#pragma unroll
            for (int q = 0; q < 4; ++q) {
                float va = Wv.x*a0[2*q]   + Wv.y*a1[2*q]   + Wv.z*a2[2*q]   + Wv.w*a3[2*q];
                float vb = Wv.x*a0[2*q+1] + Wv.y*a1[2*q+1] + Wv.z*a2[2*q+1] + Wv.w*a3[2*q+1];
                up[q] = pack2(va, vb);
            }
            *(uint4*)&vals[0][sp][sub*8] = u;
        }
        __syncthreads();

#pragma unroll 1
        for (int it = it0; it < it0 + 18; ++it) {
            const int cur = it & 1, nxt = cur ^ 1;
            const bool pre = (it < it0 + 17);

            float g0[8], g1[8], g2[8], g3[8];
            float4 Wv;
            if (pre) {
                // ---- issue next-iter gathers (latency hides under MFMA)
                const int itn = it + 1;
                const int chunk = itn/9, k2n = itn - 9*chunk;
                const int4 I = pI[k2n][sp];
                Wv = pW[k2n][sp];
                const char* xc = xB + (long)(chunk*32 + sub*8) * (NHW*4);
#pragma unroll
                for (int q = 0; q < 8; ++q) {
                    const char* p = xc + q*(NHW*4);
                    g0[q] = *(const float*)(p + I.x);
                    g1[q] = *(const float*)(p + I.y);
                    g2[q] = *(const float*)(p + I.z);
                    g3[q] = *(const float*)(p + I.w);
                }
                DMA(itn, nxt);
            } else if (og == 0) {
                DMA(18, nxt);
            }
            __builtin_amdgcn_sched_barrier(0);

            // ---- MFMA from LDS (K=32), conflict-free padded A-rows
            {
                short8 bf0 = *(const short8*)&vals[cur][pxq*32 + n][8*g];
                short8 bf1 = *(const short8*)&vals[cur][pxq*32 + 16 + n][8*g];
#pragma unroll
                for (int rf = 0; rf < 4; ++rf) {
                    short8 af = *(const short8*)&wslab[cur][(ch*64 + rf*16 + n)*36 + 8*g];
                    acc[rf][0] = __builtin_amdgcn_mfma_f32_16x16x32_bf16(af, bf0, acc[rf][0], 0,0,0);
                    acc[rf][1] = __builtin_amdgcn_mfma_f32_16x16x32_bf16(af, bf1, acc[rf][1], 0,0,0);
                }
            }
            __builtin_amdgcn_sched_barrier(0);

            if (pre) {
                // ---- finish sampling: weight, pack bf16, LDS write
                uint4 u; unsigned* up = (unsigned*)&u;
#pragma unroll
                for (int q = 0; q < 4; ++q) {
                    float va = Wv.x*g0[2*q]   + Wv.y*g1[2*q]   + Wv.z*g2[2*q]   + Wv.w*g3[2*q];
                    float vb = Wv.x*g0[2*q+1] + Wv.y*g1[2*q+1] + Wv.z*g2[2*q+1] + Wv.w*g3[2*q+1];
                    up[q] = pack2(va, vb);
                }
                *(uint4*)&vals[nxt][sp][sub*8] = u;
            }
            __syncthreads();
        }
    }

    // ---- epilogue
#pragma unroll
    for (int rf = 0; rf < 4; ++rf) {
#pragma unroll
        for (int pxb = 0; pxb < 2; ++pxb) {
            const int px = pxq*32 + pxb*16 + n;
#pragma unroll
            for (int r = 0; r < 4; ++r) {
                const int cout = ch*64 + rf*16 + 4*g + r;
                out[((b*NCOUT + cout)*NH + ho)*NW + px] = acc[rf][pxb][r] + bias[cout];
            }
        }
    }
}

// ---------------------------------------------------------------------------
extern "C" void kernel_launch(void* const* d_in, const int* in_sizes, int n_in,
                              void* d_out, int out_size, void* d_ws, size_t ws_size,
                              hipStream_t stream)
{
    const float* x      = (const float*)d_in[0];
    const float* w_off  = (const float*)d_in[1];
    const float* b_off  = (const float*)d_in[2];
    const float* weight = (const float*)d_in[3];
    const float* bias   = (const float*)d_in[4];
    float* out = (float*)d_out;
    float* ws  = (float*)d_ws;

    hipLaunchKernelGGL(wtrans_kernel, dim3(936), dim3(256), 0, stream,
                       w_off, weight, ws);
    hipLaunchKernelGGL(offconv_kernel, dim3(NB*NH*2), dim3(256), 0, stream,
                       x, b_off, ws);
    hipLaunchKernelGGL(deform_kernel, dim3(NB*NH), dim3(512), 0, stream,
                       x, ws, bias, out);
}

// Round 6
// 170.003 us; speedup vs baseline: 1.6535x; 1.6535x over previous
//
#include <hip/hip_runtime.h>
#include <math.h>

#define NB 4
#define NC 128
#define NH 128
#define NW 128
#define NHW (NH*NW)
#define NCOUT 128

// ws float offsets
#define SY_OFF 0
#define SX_OFF 1179648
#define MK_OFF 2359296
#define WOFF_OFF 3538944    // bf16 wA_off: 64*1152 shorts
#define WMAIN_OFF 3575808   // bf16 main weights, 36 PADDED slabs [128][36] shorts
#define XT_OFF 3659776      // bf16 xT[b][y][x][c] : 8388608 shorts (NHWC)
// total ws use: (3659776 + 4194304) * 4 B ~= 31.4 MB

typedef short short8 __attribute__((ext_vector_type(8)));
typedef float f32x4 __attribute__((ext_vector_type(4)));

__device__ inline short f2bf(float f) {
    unsigned u = __float_as_uint(f);
    u = (u + 0x7FFFu + ((u >> 16) & 1u)) >> 16;   // RNE
    return (short)u;
}
// packed RNE f32x2 -> bf16x2 in one instruction
__device__ inline unsigned pack2(float lo, float hi) {
    unsigned r;
    asm("v_cvt_pk_bf16_f32 %0, %1, %2" : "=v"(r) : "v"(lo), "v"(hi));
    return r;
}
__device__ inline float bflo(unsigned u) { return __uint_as_float(u << 16); }
__device__ inline float bfhi(unsigned u) { return __uint_as_float(u & 0xffff0000u); }

__device__ inline void gload_lds16(const void* g, void* l) {
    __builtin_amdgcn_global_load_lds(
        (const __attribute__((address_space(1))) unsigned int*)g,
        (__attribute__((address_space(3))) unsigned int*)l, 16, 0, 0);
}

// ---------------------------------------------------------------------------
// wtrans: offset-conv table [cout][k2][cin] (pad 64) +
//         main table: 36 PADDED slabs [(chunk*9+k2)][cout][36] (cols 32..35 = 0)
// ---------------------------------------------------------------------------
__global__ void wtrans_kernel(const float* __restrict__ w_off,
                              const float* __restrict__ weight,
                              float* __restrict__ ws)
{
    int i = blockIdx.x * 256 + threadIdx.x;
    if (i < 64*1152) {
        int cout = i / 1152, rem = i - cout*1152;
        int k2 = rem >> 7, cin = rem & 127;
        float v = (cout < 54) ? w_off[(cout*NC + cin)*9 + k2] : 0.f;
        ((short*)(ws + WOFF_OFF))[i] = f2bf(v);
    } else if (i < 64*1152 + 36*4608) {
        int j = i - 64*1152;
        int s = j / 4608, rem = j - s*4608;
        int row = rem / 36, c = rem - row*36;
        int chunk = s / 9, k2 = s - 9*chunk;
        float v = (c < 32) ? weight[(row*NC + chunk*32 + c)*9 + k2] : 0.f;
        ((short*)(ws + WMAIN_OFF))[j] = f2bf(v);
    }
}

// ---------------------------------------------------------------------------
// offconv: 3x3 conv, 54 ch (pad 64) via MFMA. Block = (b, ho, half-row 64px).
// ALSO dumps its staged center row to xT (NHWC bf16) for deform's gathers.
// ---------------------------------------------------------------------------
__global__ __launch_bounds__(256) void offconv_kernel(
    const float* __restrict__ x, const float* __restrict__ b_off,
    float* __restrict__ ws)
{
    __shared__ short xs[3][66][40];
    int bid = blockIdx.x;
    bid = (bid & 7) * 128 + (bid >> 3);     // XCD swizzle (1024 = 8*128)
    const int b   = bid >> 8;
    const int ho  = (bid >> 1) & 127;
    const int wb  = (bid & 1) * 64;
    const int tid = threadIdx.x;
    const int lane = tid & 63;
    const int wid = tid >> 6;
    const int n = lane & 15, g = lane >> 4;
    const int px0 = 16 * wid;
    const short* wA = (const short*)(ws + WOFF_OFF);
    short* xT = (short*)(ws + XT_OFF);

    f32x4 acc[4];
#pragma unroll
    for (int rf = 0; rf < 4; ++rf) acc[rf] = (f32x4){0.f,0.f,0.f,0.f};

    for (int c0 = 0; c0 < NC; c0 += 32) {
        __syncthreads();
        for (int e = tid; e < 3*66*4; e += 256) {
            int col = e % 66;
            int t2  = e / 66;
            int cg  = t2 & 3;
            int ky  = t2 >> 2;
            int y    = ho - 1 + ky;
            int gcol = wb + col - 1;
            float v[8];
            if ((unsigned)y < NH && (unsigned)gcol < NW) {
                const float* p = x + ((b*NC + c0 + 8*cg)*NH + y)*NW + gcol;
#pragma unroll
                for (int q = 0; q < 8; ++q) v[q] = p[q*NHW];
            } else {
#pragma unroll
                for (int q = 0; q < 8; ++q) v[q] = 0.f;
            }
            uint4 u = make_uint4(pack2(v[0],v[1]), pack2(v[2],v[3]),
                                 pack2(v[4],v[5]), pack2(v[6],v[7]));
            *(uint4*)&xs[ky][col][8*cg] = u;
        }
        __syncthreads();

#pragma unroll
        for (int k2 = 0; k2 < 9; ++k2) {
            const int ky = k2 / 3, kx = k2 % 3;
            short8 bf = *(const short8*)&xs[ky][px0 + n + kx][8*g];
#pragma unroll
            for (int rf = 0; rf < 4; ++rf) {
                short8 af = *(const short8*)&wA[((16*rf + n)*9 + k2)*128 + c0 + 8*g];
                acc[rf] = __builtin_amdgcn_mfma_f32_16x16x32_bf16(af, bf, acc[rf], 0,0,0);
            }
        }

        // dump staged center row -> xT[b][ho][wb..wb+63][c0..c0+31] (NHWC bf16)
        {
            const int px = tid >> 2, cq = tid & 3;
            short8 v = *(const short8*)&xs[1][px + 1][8*cq];
            *(short8*)&xT[(((long)b*NH + ho)*NW + wb + px)*NC + c0 + 8*cq] = v;
        }
    }

    const int px = wb + px0 + n;
#pragma unroll
    for (int rf = 0; rf < 4; ++rf) {
#pragma unroll
        for (int r = 0; r < 4; ++r) {
            int cout = 16*rf + 4*g + r;
            if (cout >= 54) continue;
            float v = acc[rf][r] + b_off[cout];
            if (cout < 36) {
                int og = cout / 18, rem = cout - 18*og;
                int k2c = rem >> 1, d = cout & 1;
                float base = d ? (float)(px - 1 + (k2c % 3))
                              : (float)(ho - 1 + (k2c / 3));
                ws[(d ? SX_OFF : SY_OFF) + (((b*2+og)*9 + k2c)*NHW) + ho*NW + px] = v + base;
            } else {
                int cc = cout - 36;
                int og = cc / 9, k2c = cc - 9*og;
                ws[MK_OFF + (((b*2+og)*9 + k2c)*NHW) + ho*NW + px] = 1.f/(1.f+expf(-v));
            }
        }
    }
}

// ---------------------------------------------------------------------------
// deform: block = (b, ho): 128 px x 128 cout, 512 threads = 8 waves.
// Gathers from NHWC bf16 xT: 4 x dwordx4 per thread per iter (8ch x 4 corners).
// cin-chunk outer, k2 inner; weight slabs double-buffered via global_load_lds.
// ---------------------------------------------------------------------------
__global__ __launch_bounds__(512, 4) void deform_kernel(
    const float* __restrict__ ws_c, float* __restrict__ ws,
    const float* __restrict__ bias, float* __restrict__ out)
{
    __shared__ int4   pI[9][128];         // 18432 B (xT byte offsets)
    __shared__ float4 pW[9][128];         // 18432 B
    __shared__ short  vals[2][128][40];   // 20480 B
    __shared__ short  wslab[2][4608];     // 18432 B, [128][36] padded rows

    int bid = blockIdx.x;
    bid = (bid & 7) * 64 + (bid >> 3);      // XCD swizzle (512 = 8*64)
    const int b   = bid >> 7;
    const int ho  = bid & 127;
    const int tid = threadIdx.x;
    const int lane = tid & 63;
    const int wid = tid >> 6;               // 0..7
    const int n = lane & 15, g = lane >> 4;
    const int ch  = wid & 1;                // cout half (MFMA role)
    const int pxq = wid >> 1;               // px quarter (MFMA role)
    const int sp  = tid & 127;              // pixel (sampling role)
    const int sub = tid >> 7;               // 8-cin subgroup (sampling role)
    const short* wmn = (const short*)(ws + WMAIN_OFF);
    const char*  xTb = (const char*)((const short*)(ws + XT_OFF) + (long)b*NH*NW*NC);

    f32x4 acc[4][2];
#pragma unroll
    for (int rf = 0; rf < 4; ++rf) {
        acc[rf][0] = (f32x4){0.f,0.f,0.f,0.f};
        acc[rf][1] = (f32x4){0.f,0.f,0.f,0.f};
    }

    auto DMA = [&](int slabIdx, int buf) {
        const short* src = wmn + slabIdx*4608;
        gload_lds16(src + tid*8, &wslab[buf][tid*8]);
        if (tid < 64) gload_lds16(src + 4096 + tid*8, &wslab[buf][4096 + tid*8]);
    };

    // interp 8ch from 4 corner uint4s, pack, write to vals
    auto FIN = [&](const uint4& A, const uint4& Bc, const uint4& Cc, const uint4& D,
                   const float4& Wv, int buf) {
        uint4 u; unsigned* up = (unsigned*)&u;
        const unsigned* a = (const unsigned*)&A;
        const unsigned* bq = (const unsigned*)&Bc;
        const unsigned* c = (const unsigned*)&Cc;
        const unsigned* d = (const unsigned*)&D;
#pragma unroll
        for (int e = 0; e < 4; ++e) {
            float lo = Wv.x*bflo(a[e]) + Wv.y*bflo(bq[e]) + Wv.z*bflo(c[e]) + Wv.w*bflo(d[e]);
            float hi = Wv.x*bfhi(a[e]) + Wv.y*bfhi(bq[e]) + Wv.z*bfhi(c[e]) + Wv.w*bfhi(d[e]);
            up[e] = pack2(lo, hi);
        }
        *(uint4*)&vals[buf][sp][sub*8] = u;
    };

    DMA(0, 0);   // prologue: slab 0

#pragma unroll 1
    for (int og = 0; og < 2; ++og) {
        if (og) __syncthreads();
        // ---- build bilinear params for this og (pI = xT byte offsets)
        for (int e = tid; e < 1152; e += 512) {
            const int k2 = e >> 7, px = e & 127;
            const int sidx = (((b*2+og)*9 + k2)*NHW) + ho*NW + px;
            const float sy = ws[SY_OFF + sidx];
            const float sx = ws[SX_OFF + sidx];
            const float m  = ws[MK_OFF + sidx];
            const float y0f = floorf(sy), x0f = floorf(sx);
            const float ly = sy - y0f, lx = sx - x0f;
            const int y0 = (int)y0f, x0i = (int)x0f;
            const int y1 = y0 + 1, x1 = x0i + 1;
            const bool vy0 = (unsigned)y0 < NH, vy1 = (unsigned)y1 < NH;
            const bool vx0 = (unsigned)x0i < NW, vx1 = (unsigned)x1 < NW;
            const int cy0 = min(max(y0,0),NH-1), cy1 = min(max(y1,0),NH-1);
            const int cx0 = min(max(x0i,0),NW-1), cx1 = min(max(x1,0),NW-1);
            pI[k2][px] = make_int4((cy0*NW + cx0)*256, (cy0*NW + cx1)*256,
                                   (cy1*NW + cx0)*256, (cy1*NW + cx1)*256);
            pW[k2][px] = make_float4(
                (vy0 && vx0) ? (1.f-ly)*(1.f-lx)*m : 0.f,
                (vy0 && vx1) ? (1.f-ly)*lx*m       : 0.f,
                (vy1 && vx0) ? ly*(1.f-lx)*m       : 0.f,
                (vy1 && vx1) ? ly*lx*m             : 0.f);
        }
        __syncthreads();

        const int it0 = og*18;

        // prologue sample for it0
        {
            const int chunk = it0/9, k2n = it0 - 9*chunk;
            const int4  I  = pI[k2n][sp];
            const float4 Wv = pW[k2n][sp];
            const int cofs = chunk*64 + sub*16;
            uint4 A  = *(const uint4*)(xTb + I.x + cofs);
            uint4 Bc = *(const uint4*)(xTb + I.y + cofs);
            uint4 Cc = *(const uint4*)(xTb + I.z + cofs);
            uint4 D  = *(const uint4*)(xTb + I.w + cofs);
            FIN(A, Bc, Cc, D, Wv, 0);
        }
        __syncthreads();

#pragma unroll 1
        for (int it = it0; it < it0 + 18; ++it) {
            const int cur = it & 1, nxt = cur ^ 1;
            const bool pre = (it < it0 + 17);

            uint4 A, Bc, Cc, D;
            float4 Wv;
            if (pre) {
                // ---- issue next-iter gathers (hide under MFMA)
                const int itn = it + 1;
                const int chunk = itn/9, k2n = itn - 9*chunk;
                const int4 I = pI[k2n][sp];
                Wv = pW[k2n][sp];
                const int cofs = chunk*64 + sub*16;
                A  = *(const uint4*)(xTb + I.x + cofs);
                Bc = *(const uint4*)(xTb + I.y + cofs);
                Cc = *(const uint4*)(xTb + I.z + cofs);
                D  = *(const uint4*)(xTb + I.w + cofs);
                DMA(itn, nxt);
            } else if (og == 0) {
                DMA(18, nxt);
            }
            __builtin_amdgcn_sched_barrier(0);

            // ---- MFMA from LDS (K=32)
            {
                short8 bf0 = *(const short8*)&vals[cur][pxq*32 + n][8*g];
                short8 bf1 = *(const short8*)&vals[cur][pxq*32 + 16 + n][8*g];
#pragma unroll
                for (int rf = 0; rf < 4; ++rf) {
                    short8 af = *(const short8*)&wslab[cur][(ch*64 + rf*16 + n)*36 + 8*g];
                    acc[rf][0] = __builtin_amdgcn_mfma_f32_16x16x32_bf16(af, bf0, acc[rf][0], 0,0,0);
                    acc[rf][1] = __builtin_amdgcn_mfma_f32_16x16x32_bf16(af, bf1, acc[rf][1], 0,0,0);
                }
            }
            __builtin_amdgcn_sched_barrier(0);

            if (pre) FIN(A, Bc, Cc, D, Wv, nxt);
            __syncthreads();
        }
    }

    // ---- epilogue
#pragma unroll
    for (int rf = 0; rf < 4; ++rf) {
#pragma unroll
        for (int pxb = 0; pxb < 2; ++pxb) {
            const int px = pxq*32 + pxb*16 + n;
#pragma unroll
            for (int r = 0; r < 4; ++r) {
                const int cout = ch*64 + rf*16 + 4*g + r;
                out[((b*NCOUT + cout)*NH + ho)*NW + px] = acc[rf][pxb][r] + bias[cout];
            }
        }
    }
}

// ---------------------------------------------------------------------------
extern "C" void kernel_launch(void* const* d_in, const int* in_sizes, int n_in,
                              void* d_out, int out_size, void* d_ws, size_t ws_size,
                              hipStream_t stream)
{
    const float* x      = (const float*)d_in[0];
    const float* w_off  = (const float*)d_in[1];
    const float* b_off  = (const float*)d_in[2];
    const float* weight = (const float*)d_in[3];
    const float* bias   = (const float*)d_in[4];
    float* out = (float*)d_out;
    float* ws  = (float*)d_ws;

    hipLaunchKernelGGL(wtrans_kernel, dim3(936), dim3(256), 0, stream,
                       w_off, weight, ws);
    hipLaunchKernelGGL(offconv_kernel, dim3(NB*NH*2), dim3(256), 0, stream,
                       x, b_off, ws);
    hipLaunchKernelGGL(deform_kernel, dim3(NB*NH), dim3(512), 0, stream,
                       ws, ws, bias, out);
}

// Round 7
// 132.774 us; speedup vs baseline: 2.1172x; 1.2804x over previous
//
#include <hip/hip_runtime.h>
#include <math.h>

#define NB 4
#define NC 128
#define NH 128
#define NW 128
#define NHW (NH*NW)
#define NCOUT 128

// ws float offsets
#define SY_OFF 0
#define SX_OFF 1179648
#define MK_OFF 2359296
#define WOFF_OFF 3538944    // bf16 wA_off: 64*1152 shorts
#define WMAIN_OFF 3575808   // bf16 main weights, 36 PADDED slabs [128][36] shorts
#define XT_OFF 3659776      // bf16 xT[b][cg16][y][x][8ch] : 8388608 shorts
// total ws use: (3659776 + 4194304) * 4 B ~= 31.4 MB

typedef short short8 __attribute__((ext_vector_type(8)));
typedef float f32x4 __attribute__((ext_vector_type(4)));

__device__ inline short f2bf(float f) {
    unsigned u = __float_as_uint(f);
    u = (u + 0x7FFFu + ((u >> 16) & 1u)) >> 16;   // RNE
    return (short)u;
}
// packed RNE f32x2 -> bf16x2 in one instruction
__device__ inline unsigned pack2(float lo, float hi) {
    unsigned r;
    asm("v_cvt_pk_bf16_f32 %0, %1, %2" : "=v"(r) : "v"(lo), "v"(hi));
    return r;
}
__device__ inline float bflo(unsigned u) { return __uint_as_float(u << 16); }
__device__ inline float bfhi(unsigned u) { return __uint_as_float(u & 0xffff0000u); }

__device__ inline void gload_lds16(const void* g, void* l) {
    __builtin_amdgcn_global_load_lds(
        (const __attribute__((address_space(1))) unsigned int*)g,
        (__attribute__((address_space(3))) unsigned int*)l, 16, 0, 0);
}

// ---------------------------------------------------------------------------
// wtrans: offset-conv table [cout][k2][cin] (pad 64) +
//         main table: 36 PADDED slabs [(chunk*9+k2)][cout][36] (cols 32..35 = 0)
// ---------------------------------------------------------------------------
__global__ void wtrans_kernel(const float* __restrict__ w_off,
                              const float* __restrict__ weight,
                              float* __restrict__ ws)
{
    int i = blockIdx.x * 256 + threadIdx.x;
    if (i < 64*1152) {
        int cout = i / 1152, rem = i - cout*1152;
        int k2 = rem >> 7, cin = rem & 127;
        float v = (cout < 54) ? w_off[(cout*NC + cin)*9 + k2] : 0.f;
        ((short*)(ws + WOFF_OFF))[i] = f2bf(v);
    } else if (i < 64*1152 + 36*4608) {
        int j = i - 64*1152;
        int s = j / 4608, rem = j - s*4608;
        int row = rem / 36, c = rem - row*36;
        int chunk = s / 9, k2 = s - 9*chunk;
        float v = (c < 32) ? weight[(row*NC + chunk*32 + c)*9 + k2] : 0.f;
        ((short*)(ws + WMAIN_OFF))[j] = f2bf(v);
    }
}

// ---------------------------------------------------------------------------
// offconv: 3x3 conv, 54 ch (pad 64) via MFMA. Block = (b, ho, half-row 64px).
// ALSO dumps its staged center row to xT[b][cg][y][x][8ch] for deform.
// ---------------------------------------------------------------------------
__global__ __launch_bounds__(256) void offconv_kernel(
    const float* __restrict__ x, const float* __restrict__ b_off,
    float* __restrict__ ws)
{
    __shared__ short xs[3][66][40];
    int bid = blockIdx.x;
    bid = (bid & 7) * 128 + (bid >> 3);     // XCD swizzle (1024 = 8*128)
    const int b   = bid >> 8;
    const int ho  = (bid >> 1) & 127;
    const int wb  = (bid & 1) * 64;
    const int tid = threadIdx.x;
    const int lane = tid & 63;
    const int wid = tid >> 6;
    const int n = lane & 15, g = lane >> 4;
    const int px0 = 16 * wid;
    const short* wA = (const short*)(ws + WOFF_OFF);
    short* xT = (short*)(ws + XT_OFF);

    f32x4 acc[4];
#pragma unroll
    for (int rf = 0; rf < 4; ++rf) acc[rf] = (f32x4){0.f,0.f,0.f,0.f};

    for (int c0 = 0; c0 < NC; c0 += 32) {
        __syncthreads();
        for (int e = tid; e < 3*66*4; e += 256) {
            int col = e % 66;
            int t2  = e / 66;
            int cg  = t2 & 3;
            int ky  = t2 >> 2;
            int y    = ho - 1 + ky;
            int gcol = wb + col - 1;
            float v[8];
            if ((unsigned)y < NH && (unsigned)gcol < NW) {
                const float* p = x + ((b*NC + c0 + 8*cg)*NH + y)*NW + gcol;
#pragma unroll
                for (int q = 0; q < 8; ++q) v[q] = p[q*NHW];
            } else {
#pragma unroll
                for (int q = 0; q < 8; ++q) v[q] = 0.f;
            }
            uint4 u = make_uint4(pack2(v[0],v[1]), pack2(v[2],v[3]),
                                 pack2(v[4],v[5]), pack2(v[6],v[7]));
            *(uint4*)&xs[ky][col][8*cg] = u;
        }
        __syncthreads();

#pragma unroll
        for (int k2 = 0; k2 < 9; ++k2) {
            const int ky = k2 / 3, kx = k2 % 3;
            short8 bf = *(const short8*)&xs[ky][px0 + n + kx][8*g];
#pragma unroll
            for (int rf = 0; rf < 4; ++rf) {
                short8 af = *(const short8*)&wA[((16*rf + n)*9 + k2)*128 + c0 + 8*g];
                acc[rf] = __builtin_amdgcn_mfma_f32_16x16x32_bf16(af, bf, acc[rf], 0,0,0);
            }
        }

        // dump center row -> xT[b][c0/8 + cq][ho][wb+px][8ch]
        {
            const int px = tid >> 2, cq = tid & 3;
            short8 v = *(const short8*)&xs[1][px + 1][8*cq];
            const long cg = (long)b*16 + (c0 >> 3) + cq;
            *(short8*)&xT[((cg*NH + ho)*NW + wb + px)*8] = v;
        }
    }

    const int px = wb + px0 + n;
#pragma unroll
    for (int rf = 0; rf < 4; ++rf) {
#pragma unroll
        for (int r = 0; r < 4; ++r) {
            int cout = 16*rf + 4*g + r;
            if (cout >= 54) continue;
            float v = acc[rf][r] + b_off[cout];
            if (cout < 36) {
                int og = cout / 18, rem = cout - 18*og;
                int k2c = rem >> 1, d = cout & 1;
                float base = d ? (float)(px - 1 + (k2c % 3))
                              : (float)(ho - 1 + (k2c / 3));
                ws[(d ? SX_OFF : SY_OFF) + (((b*2+og)*9 + k2c)*NHW) + ho*NW + px] = v + base;
            } else {
                int cc = cout - 36;
                int og = cc / 9, k2c = cc - 9*og;
                ws[MK_OFF + (((b*2+og)*9 + k2c)*NHW) + ho*NW + px] = 1.f/(1.f+expf(-v));
            }
        }
    }
}

// ---------------------------------------------------------------------------
// deform: block = (b, ho): 128 px x 128 cout, 512 threads = 8 waves.
// Gathers from xT[b][cg][y][x][8ch]: px stride 16B -> lanes share cache lines.
// cin-chunk outer, k2 inner; weight slabs double-buffered via global_load_lds.
// ---------------------------------------------------------------------------
__global__ __launch_bounds__(512, 4) void deform_kernel(
    const float* __restrict__ ws_c, float* __restrict__ ws,
    const float* __restrict__ bias, float* __restrict__ out)
{
    __shared__ int4   pI[9][128];         // 18432 B (plane-local byte offsets)
    __shared__ float4 pW[9][128];         // 18432 B
    __shared__ short  vals[2][128][40];   // 20480 B
    __shared__ short  wslab[2][4608];     // 18432 B, [128][36] padded rows

    int bid = blockIdx.x;
    bid = (bid & 7) * 64 + (bid >> 3);      // XCD swizzle (512 = 8*64)
    const int b   = bid >> 7;
    const int ho  = bid & 127;
    const int tid = threadIdx.x;
    const int lane = tid & 63;
    const int wid = tid >> 6;               // 0..7
    const int n = lane & 15, g = lane >> 4;
    const int ch  = wid & 1;                // cout half (MFMA role)
    const int pxq = wid >> 1;               // px quarter (MFMA role)
    const int sp  = tid & 127;              // pixel (sampling role)
    const int sub = tid >> 7;               // 8-ch group within chunk (0..3)
    const short* wmn = (const short*)(ws + WMAIN_OFF);
    const char*  xTb = (const char*)((const short*)(ws + XT_OFF) + (long)b*16*NHW*8);

    f32x4 acc[4][2];
#pragma unroll
    for (int rf = 0; rf < 4; ++rf) {
        acc[rf][0] = (f32x4){0.f,0.f,0.f,0.f};
        acc[rf][1] = (f32x4){0.f,0.f,0.f,0.f};
    }

    auto DMA = [&](int slabIdx, int buf) {
        const short* src = wmn + slabIdx*4608;
        gload_lds16(src + tid*8, &wslab[buf][tid*8]);
        if (tid < 64) gload_lds16(src + 4096 + tid*8, &wslab[buf][4096 + tid*8]);
    };

    // interp 8ch from 4 corner uint4s, pack, write to vals
    auto FIN = [&](const uint4& A, const uint4& Bc, const uint4& Cc, const uint4& D,
                   const float4& Wv, int buf) {
        uint4 u; unsigned* up = (unsigned*)&u;
        const unsigned* a = (const unsigned*)&A;
        const unsigned* bq = (const unsigned*)&Bc;
        const unsigned* c = (const unsigned*)&Cc;
        const unsigned* d = (const unsigned*)&D;
#pragma unroll
        for (int e = 0; e < 4; ++e) {
            float lo = Wv.x*bflo(a[e]) + Wv.y*bflo(bq[e]) + Wv.z*bflo(c[e]) + Wv.w*bflo(d[e]);
            float hi = Wv.x*bfhi(a[e]) + Wv.y*bfhi(bq[e]) + Wv.z*bfhi(c[e]) + Wv.w*bfhi(d[e]);
            up[e] = pack2(lo, hi);
        }
        *(uint4*)&vals[buf][sp][sub*8] = u;
    };

    DMA(0, 0);   // prologue: slab 0

#pragma unroll 1
    for (int og = 0; og < 2; ++og) {
        if (og) __syncthreads();
        // ---- build bilinear params for this og (pI = plane-local byte offsets)
        for (int e = tid; e < 1152; e += 512) {
            const int k2 = e >> 7, px = e & 127;
            const int sidx = (((b*2+og)*9 + k2)*NHW) + ho*NW + px;
            const float sy = ws[SY_OFF + sidx];
            const float sx = ws[SX_OFF + sidx];
            const float m  = ws[MK_OFF + sidx];
            const float y0f = floorf(sy), x0f = floorf(sx);
            const float ly = sy - y0f, lx = sx - x0f;
            const int y0 = (int)y0f, x0i = (int)x0f;
            const int y1 = y0 + 1, x1 = x0i + 1;
            const bool vy0 = (unsigned)y0 < NH, vy1 = (unsigned)y1 < NH;
            const bool vx0 = (unsigned)x0i < NW, vx1 = (unsigned)x1 < NW;
            const int cy0 = min(max(y0,0),NH-1), cy1 = min(max(y1,0),NH-1);
            const int cx0 = min(max(x0i,0),NW-1), cx1 = min(max(x1,0),NW-1);
            pI[k2][px] = make_int4((cy0*NW + cx0)*16, (cy0*NW + cx1)*16,
                                   (cy1*NW + cx0)*16, (cy1*NW + cx1)*16);
            pW[k2][px] = make_float4(
                (vy0 && vx0) ? (1.f-ly)*(1.f-lx)*m : 0.f,
                (vy0 && vx1) ? (1.f-ly)*lx*m       : 0.f,
                (vy1 && vx0) ? ly*(1.f-lx)*m       : 0.f,
                (vy1 && vx1) ? ly*lx*m             : 0.f);
        }
        __syncthreads();

        const int it0 = og*18;

        // prologue sample for it0
        {
            const int chunk = it0/9, k2n = it0 - 9*chunk;
            const int4  I  = pI[k2n][sp];
            const float4 Wv = pW[k2n][sp];
            const char* xp = xTb + (long)(chunk*4 + sub)*(NHW*16);
            uint4 A  = *(const uint4*)(xp + I.x);
            uint4 Bc = *(const uint4*)(xp + I.y);
            uint4 Cc = *(const uint4*)(xp + I.z);
            uint4 D  = *(const uint4*)(xp + I.w);
            FIN(A, Bc, Cc, D, Wv, 0);
        }
        __syncthreads();

#pragma unroll 1
        for (int it = it0; it < it0 + 18; ++it) {
            const int cur = it & 1, nxt = cur ^ 1;
            const bool pre = (it < it0 + 17);

            uint4 A, Bc, Cc, D;
            float4 Wv;
            if (pre) {
                // ---- issue next-iter gathers (hide under MFMA)
                const int itn = it + 1;
                const int chunk = itn/9, k2n = itn - 9*chunk;
                const int4 I = pI[k2n][sp];
                Wv = pW[k2n][sp];
                const char* xp = xTb + (long)(chunk*4 + sub)*(NHW*16);
                A  = *(const uint4*)(xp + I.x);
                Bc = *(const uint4*)(xp + I.y);
                Cc = *(const uint4*)(xp + I.z);
                D  = *(const uint4*)(xp + I.w);
                DMA(itn, nxt);
            } else if (og == 0) {
                DMA(18, nxt);
            }
            __builtin_amdgcn_sched_barrier(0);

            // ---- MFMA from LDS (K=32)
            {
                short8 bf0 = *(const short8*)&vals[cur][pxq*32 + n][8*g];
                short8 bf1 = *(const short8*)&vals[cur][pxq*32 + 16 + n][8*g];
#pragma unroll
                for (int rf = 0; rf < 4; ++rf) {
                    short8 af = *(const short8*)&wslab[cur][(ch*64 + rf*16 + n)*36 + 8*g];
                    acc[rf][0] = __builtin_amdgcn_mfma_f32_16x16x32_bf16(af, bf0, acc[rf][0], 0,0,0);
                    acc[rf][1] = __builtin_amdgcn_mfma_f32_16x16x32_bf16(af, bf1, acc[rf][1], 0,0,0);
                }
            }
            __builtin_amdgcn_sched_barrier(0);

            if (pre) FIN(A, Bc, Cc, D, Wv, nxt);
            __syncthreads();
        }
    }

    // ---- epilogue
#pragma unroll
    for (int rf = 0; rf < 4; ++rf) {
#pragma unroll
        for (int pxb = 0; pxb < 2; ++pxb) {
            const int px = pxq*32 + pxb*16 + n;
#pragma unroll
            for (int r = 0; r < 4; ++r) {
                const int cout = ch*64 + rf*16 + 4*g + r;
                out[((b*NCOUT + cout)*NH + ho)*NW + px] = acc[rf][pxb][r] + bias[cout];
            }
        }
    }
}

// ---------------------------------------------------------------------------
extern "C" void kernel_launch(void* const* d_in, const int* in_sizes, int n_in,
                              void* d_out, int out_size, void* d_ws, size_t ws_size,
                              hipStream_t stream)
{
    const float* x      = (const float*)d_in[0];
    const float* w_off  = (const float*)d_in[1];
    const float* b_off  = (const float*)d_in[2];
    const float* weight = (const float*)d_in[3];
    const float* bias   = (const float*)d_in[4];
    float* out = (float*)d_out;
    float* ws  = (float*)d_ws;

    hipLaunchKernelGGL(wtrans_kernel, dim3(936), dim3(256), 0, stream,
                       w_off, weight, ws);
    hipLaunchKernelGGL(offconv_kernel, dim3(NB*NH*2), dim3(256), 0, stream,
                       x, b_off, ws);
    hipLaunchKernelGGL(deform_kernel, dim3(NB*NH), dim3(512), 0, stream,
                       ws, ws, bias, out);
}

// Round 8
// 90.624 us; speedup vs baseline: 3.1019x; 1.4651x over previous
//
#include <hip/hip_runtime.h>
#include <math.h>

#define NB 4
#define NC 128
#define NH 128
#define NW 128
#define NHW (NH*NW)
#define NCOUT 128

// ws float offsets
#define SY_OFF 0
#define SX_OFF 1179648
#define MK_OFF 2359296
#define WOFF_OFF 3538944    // 36 slabs [64][36] bf16 (offset-conv W) = 82944 shorts
#define WMAIN_OFF 3580416   // 36 slabs [128][36] bf16 (main W) = 165888 shorts
#define XT_OFF 3663360      // bf16 xT[b][cg16][y][x][8ch] : 8388608 shorts
// total ws use: 7857664 floats ~= 31.4 MB

typedef short short8 __attribute__((ext_vector_type(8)));
typedef float f32x4 __attribute__((ext_vector_type(4)));

__device__ inline short f2bf(float f) {
    unsigned u = __float_as_uint(f);
    u = (u + 0x7FFFu + ((u >> 16) & 1u)) >> 16;   // RNE
    return (short)u;
}
// packed RNE f32x2 -> bf16x2 in one instruction
__device__ inline unsigned pack2(float lo, float hi) {
    unsigned r;
    asm("v_cvt_pk_bf16_f32 %0, %1, %2" : "=v"(r) : "v"(lo), "v"(hi));
    return r;
}
__device__ inline float bflo(unsigned u) { return __uint_as_float(u << 16); }
__device__ inline float bfhi(unsigned u) { return __uint_as_float(u & 0xffff0000u); }

__device__ inline void gload_lds16(const void* g, void* l) {
    __builtin_amdgcn_global_load_lds(
        (const __attribute__((address_space(1))) unsigned int*)g,
        (__attribute__((address_space(3))) unsigned int*)l, 16, 0, 0);
}

// ---------------------------------------------------------------------------
// wtrans: both weight tables as padded 36-col slabs.
//   offset conv: 36 slabs [(chunk*9+k2)][64 rows][36]  (rows>=54, cols>=32 = 0)
//   main conv:   36 slabs [(chunk*9+k2)][128 rows][36] (cols>=32 = 0)
// ---------------------------------------------------------------------------
__global__ void wtrans_kernel(const float* __restrict__ w_off,
                              const float* __restrict__ weight,
                              float* __restrict__ ws)
{
    int i = blockIdx.x * 256 + threadIdx.x;
    if (i < 36*2304) {
        int s = i / 2304, rem = i - s*2304;
        int row = rem / 36, c = rem - row*36;
        int chunk = s / 9, k2 = s - 9*chunk;
        float v = (row < 54 && c < 32) ? w_off[(row*NC + chunk*32 + c)*9 + k2] : 0.f;
        ((short*)(ws + WOFF_OFF))[i] = f2bf(v);
    } else if (i < 36*2304 + 36*4608) {
        int j = i - 36*2304;
        int s = j / 4608, rem = j - s*4608;
        int row = rem / 36, c = rem - row*36;
        int chunk = s / 9, k2 = s - 9*chunk;
        float v = (c < 32) ? weight[(row*NC + chunk*32 + c)*9 + k2] : 0.f;
        ((short*)(ws + WMAIN_OFF))[j] = f2bf(v);
    }
}

// ---------------------------------------------------------------------------
// xtrans: x NCHW fp32 -> xT[b][cg][y][x][8ch] bf16. Pure BW.
// Block = (b, cg, ystripe8): 1024 blocks x 256 threads.
// ---------------------------------------------------------------------------
__global__ __launch_bounds__(256) void xtrans_kernel(
    const float* __restrict__ x, float* __restrict__ ws)
{
    short* xT = (short*)(ws + XT_OFF);
    const int bid = blockIdx.x;
    const int ys = bid & 15, cg = (bid >> 4) & 15, b = bid >> 8;
    const int col = threadIdx.x & 127, rr = threadIdx.x >> 7;
    const float* xb = x + ((long)(b*NC + cg*8))*NHW;
#pragma unroll
    for (int yy = 0; yy < 4; ++yy) {
        const int y = ys*8 + yy*2 + rr;
        const float* p = xb + y*NW + col;
        float v[8];
#pragma unroll
        for (int q = 0; q < 8; ++q) v[q] = p[q*NHW];
        uint4 u = make_uint4(pack2(v[0],v[1]), pack2(v[2],v[3]),
                             pack2(v[4],v[5]), pack2(v[6],v[7]));
        *(uint4*)&xT[(((long)(b*16+cg)*NH + y)*NW + col)*8] = u;
    }
}

// ---------------------------------------------------------------------------
// offconv: 3x3 conv (54 ch pad 64) as pure GEMM over xT.
// Block = (b, ho): 128 px x 64 cout, 512 threads = 8 waves (wave = 64c x 16px).
// B-frag: ONE predicated 16B global load per lane per iter (coalesced, L2-hot).
// A-frag: [64][36] slabs double-buffered via global_load_lds.
// ---------------------------------------------------------------------------
__global__ __launch_bounds__(512, 4) void offconv_kernel(
    float* __restrict__ ws, const float* __restrict__ b_off)
{
    __shared__ short wslab[2][2304];    // [64][36], 4608 B each
    int bid = blockIdx.x;
    bid = (bid & 7) * 64 + (bid >> 3);      // XCD swizzle (512 = 8*64)
    const int b   = bid >> 7;
    const int ho  = bid & 127;
    const int tid = threadIdx.x;
    const int lane = tid & 63;
    const int wid = tid >> 6;
    const int n = lane & 15, g = lane >> 4;
    const int px = wid*16 + n;
    const short* woff = (const short*)(ws + WOFF_OFF);
    const char*  xTb  = (const char*)((const short*)(ws + XT_OFF) + (long)b*16*NHW*8);

    f32x4 acc[4];
#pragma unroll
    for (int rf = 0; rf < 4; ++rf) acc[rf] = (f32x4){0.f,0.f,0.f,0.f};

    auto DMA = [&](int it, int buf) {
        if (tid < 288) gload_lds16(woff + it*2304 + tid*8, &wslab[buf][tid*8]);
    };
    auto LOADB = [&](int it) -> short8 {
        const int chunk = it/9, k2 = it - 9*chunk;
        const int y = ho + k2/3 - 1, xc = px + (k2%3) - 1;
        short8 bf = (short8){0,0,0,0,0,0,0,0};
        if ((unsigned)y < NH && (unsigned)xc < NW)
            bf = *(const short8*)(xTb + ((long)(chunk*4 + g)*NHW + y*NW + xc)*16);
        return bf;
    };

    DMA(0, 0);
    short8 bcur = LOADB(0);
    __syncthreads();

#pragma unroll 1
    for (int it = 0; it < 36; ++it) {
        const int cur = it & 1, nxt = cur ^ 1;
        short8 bnext;
        if (it < 35) { DMA(it+1, nxt); bnext = LOADB(it+1); }
        __builtin_amdgcn_sched_barrier(0);
#pragma unroll
        for (int rf = 0; rf < 4; ++rf) {
            short8 af = *(const short8*)&wslab[cur][(rf*16 + n)*36 + 8*g];
            acc[rf] = __builtin_amdgcn_mfma_f32_16x16x32_bf16(af, bcur, acc[rf], 0,0,0);
        }
        __syncthreads();     // drains DMA(it+1)+B(it+1); all waves done with cur
        bcur = bnext;
    }

    // epilogue: route channels -> processed sy/sx/mask
#pragma unroll
    for (int rf = 0; rf < 4; ++rf) {
#pragma unroll
        for (int r = 0; r < 4; ++r) {
            int cout = 16*rf + 4*g + r;
            if (cout >= 54) continue;
            float v = acc[rf][r] + b_off[cout];
            if (cout < 36) {
                int og = cout / 18, rem = cout - 18*og;
                int k2c = rem >> 1, d = cout & 1;
                float base = d ? (float)(px - 1 + (k2c % 3))
                              : (float)(ho - 1 + (k2c / 3));
                ws[(d ? SX_OFF : SY_OFF) + (((b*2+og)*9 + k2c)*NHW) + ho*NW + px] = v + base;
            } else {
                int cc = cout - 36;
                int og = cc / 9, k2c = cc - 9*og;
                ws[MK_OFF + (((b*2+og)*9 + k2c)*NHW) + ho*NW + px] = 1.f/(1.f+expf(-v));
            }
        }
    }
}

// ---------------------------------------------------------------------------
// deform: block = (b, ho): 128 px x 128 cout, 512 threads = 8 waves.
// Gathers from xT[b][cg][y][x][8ch]: px stride 16B -> lanes share cache lines.
// cin-chunk outer, k2 inner; weight slabs double-buffered via global_load_lds.
// ---------------------------------------------------------------------------
__global__ __launch_bounds__(512, 4) void deform_kernel(
    const float* __restrict__ ws_c, float* __restrict__ ws,
    const float* __restrict__ bias, float* __restrict__ out)
{
    __shared__ int4   pI[9][128];         // 18432 B (plane-local byte offsets)
    __shared__ float4 pW[9][128];         // 18432 B
    __shared__ short  vals[2][128][40];   // 20480 B
    __shared__ short  wslab[2][4608];     // 18432 B, [128][36] padded rows

    int bid = blockIdx.x;
    bid = (bid & 7) * 64 + (bid >> 3);      // XCD swizzle (512 = 8*64)
    const int b   = bid >> 7;
    const int ho  = bid & 127;
    const int tid = threadIdx.x;
    const int lane = tid & 63;
    const int wid = tid >> 6;               // 0..7
    const int n = lane & 15, g = lane >> 4;
    const int ch  = wid & 1;                // cout half (MFMA role)
    const int pxq = wid >> 1;               // px quarter (MFMA role)
    const int sp  = tid & 127;              // pixel (sampling role)
    const int sub = tid >> 7;               // 8-ch group within chunk (0..3)
    const short* wmn = (const short*)(ws + WMAIN_OFF);
    const char*  xTb = (const char*)((const short*)(ws + XT_OFF) + (long)b*16*NHW*8);

    f32x4 acc[4][2];
#pragma unroll
    for (int rf = 0; rf < 4; ++rf) {
        acc[rf][0] = (f32x4){0.f,0.f,0.f,0.f};
        acc[rf][1] = (f32x4){0.f,0.f,0.f,0.f};
    }

    auto DMA = [&](int slabIdx, int buf) {
        const short* src = wmn + slabIdx*4608;
        gload_lds16(src + tid*8, &wslab[buf][tid*8]);
        if (tid < 64) gload_lds16(src + 4096 + tid*8, &wslab[buf][4096 + tid*8]);
    };

    // interp 8ch from 4 corner uint4s, pack, write to vals
    auto FIN = [&](const uint4& A, const uint4& Bc, const uint4& Cc, const uint4& D,
                   const float4& Wv, int buf) {
        uint4 u; unsigned* up = (unsigned*)&u;
        const unsigned* a = (const unsigned*)&A;
        const unsigned* bq = (const unsigned*)&Bc;
        const unsigned* c = (const unsigned*)&Cc;
        const unsigned* d = (const unsigned*)&D;
#pragma unroll
        for (int e = 0; e < 4; ++e) {
            float lo = Wv.x*bflo(a[e]) + Wv.y*bflo(bq[e]) + Wv.z*bflo(c[e]) + Wv.w*bflo(d[e]);
            float hi = Wv.x*bfhi(a[e]) + Wv.y*bfhi(bq[e]) + Wv.z*bfhi(c[e]) + Wv.w*bfhi(d[e]);
            up[e] = pack2(lo, hi);
        }
        *(uint4*)&vals[buf][sp][sub*8] = u;
    };

    DMA(0, 0);   // prologue: slab 0

#pragma unroll 1
    for (int og = 0; og < 2; ++og) {
        if (og) __syncthreads();
        // ---- build bilinear params for this og (pI = plane-local byte offsets)
        for (int e = tid; e < 1152; e += 512) {
            const int k2 = e >> 7, px = e & 127;
            const int sidx = (((b*2+og)*9 + k2)*NHW) + ho*NW + px;
            const float sy = ws[SY_OFF + sidx];
            const float sx = ws[SX_OFF + sidx];
            const float m  = ws[MK_OFF + sidx];
            const float y0f = floorf(sy), x0f = floorf(sx);
            const float ly = sy - y0f, lx = sx - x0f;
            const int y0 = (int)y0f, x0i = (int)x0f;
            const int y1 = y0 + 1, x1 = x0i + 1;
            const bool vy0 = (unsigned)y0 < NH, vy1 = (unsigned)y1 < NH;
            const bool vx0 = (unsigned)x0i < NW, vx1 = (unsigned)x1 < NW;
            const int cy0 = min(max(y0,0),NH-1), cy1 = min(max(y1,0),NH-1);
            const int cx0 = min(max(x0i,0),NW-1), cx1 = min(max(x1,0),NW-1);
            pI[k2][px] = make_int4((cy0*NW + cx0)*16, (cy0*NW + cx1)*16,
                                   (cy1*NW + cx0)*16, (cy1*NW + cx1)*16);
            pW[k2][px] = make_float4(
                (vy0 && vx0) ? (1.f-ly)*(1.f-lx)*m : 0.f,
                (vy0 && vx1) ? (1.f-ly)*lx*m       : 0.f,
                (vy1 && vx0) ? ly*(1.f-lx)*m       : 0.f,
                (vy1 && vx1) ? ly*lx*m             : 0.f);
        }
        __syncthreads();

        const int it0 = og*18;

        // prologue sample for it0
        {
            const int chunk = it0/9, k2n = it0 - 9*chunk;
            const int4  I  = pI[k2n][sp];
            const float4 Wv = pW[k2n][sp];
            const char* xp = xTb + (long)(chunk*4 + sub)*(NHW*16);
            uint4 A  = *(const uint4*)(xp + I.x);
            uint4 Bc = *(const uint4*)(xp + I.y);
            uint4 Cc = *(const uint4*)(xp + I.z);
            uint4 D  = *(const uint4*)(xp + I.w);
            FIN(A, Bc, Cc, D, Wv, 0);
        }
        __syncthreads();

#pragma unroll 1
        for (int it = it0; it < it0 + 18; ++it) {
            const int cur = it & 1, nxt = cur ^ 1;
            const bool pre = (it < it0 + 17);

            uint4 A, Bc, Cc, D;
            float4 Wv;
            if (pre) {
                // ---- issue next-iter gathers (hide under MFMA)
                const int itn = it + 1;
                const int chunk = itn/9, k2n = itn - 9*chunk;
                const int4 I = pI[k2n][sp];
                Wv = pW[k2n][sp];
                const char* xp = xTb + (long)(chunk*4 + sub)*(NHW*16);
                A  = *(const uint4*)(xp + I.x);
                Bc = *(const uint4*)(xp + I.y);
                Cc = *(const uint4*)(xp + I.z);
                D  = *(const uint4*)(xp + I.w);
                DMA(itn, nxt);
            } else if (og == 0) {
                DMA(18, nxt);
            }
            __builtin_amdgcn_sched_barrier(0);

            // ---- MFMA from LDS (K=32)
            {
                short8 bf0 = *(const short8*)&vals[cur][pxq*32 + n][8*g];
                short8 bf1 = *(const short8*)&vals[cur][pxq*32 + 16 + n][8*g];
#pragma unroll
                for (int rf = 0; rf < 4; ++rf) {
                    short8 af = *(const short8*)&wslab[cur][(ch*64 + rf*16 + n)*36 + 8*g];
                    acc[rf][0] = __builtin_amdgcn_mfma_f32_16x16x32_bf16(af, bf0, acc[rf][0], 0,0,0);
                    acc[rf][1] = __builtin_amdgcn_mfma_f32_16x16x32_bf16(af, bf1, acc[rf][1], 0,0,0);
                }
            }
            __builtin_amdgcn_sched_barrier(0);

            if (pre) FIN(A, Bc, Cc, D, Wv, nxt);
            __syncthreads();
        }
    }

    // ---- epilogue
#pragma unroll
    for (int rf = 0; rf < 4; ++rf) {
#pragma unroll
        for (int pxb = 0; pxb < 2; ++pxb) {
            const int px = pxq*32 + pxb*16 + n;
#pragma unroll
            for (int r = 0; r < 4; ++r) {
                const int cout = ch*64 + rf*16 + 4*g + r;
                out[((b*NCOUT + cout)*NH + ho)*NW + px] = acc[rf][pxb][r] + bias[cout];
            }
        }
    }
}

// ---------------------------------------------------------------------------
extern "C" void kernel_launch(void* const* d_in, const int* in_sizes, int n_in,
                              void* d_out, int out_size, void* d_ws, size_t ws_size,
                              hipStream_t stream)
{
    const float* x      = (const float*)d_in[0];
    const float* w_off  = (const float*)d_in[1];
    const float* b_off  = (const float*)d_in[2];
    const float* weight = (const float*)d_in[3];
    const float* bias   = (const float*)d_in[4];
    float* out = (float*)d_out;
    float* ws  = (float*)d_ws;

    hipLaunchKernelGGL(wtrans_kernel, dim3(972), dim3(256), 0, stream,
                       w_off, weight, ws);
    hipLaunchKernelGGL(xtrans_kernel, dim3(1024), dim3(256), 0, stream,
                       x, ws);
    hipLaunchKernelGGL(offconv_kernel, dim3(NB*NH), dim3(512), 0, stream,
                       ws, b_off);
    hipLaunchKernelGGL(deform_kernel, dim3(NB*NH), dim3(512), 0, stream,
                       ws, ws, bias, out);
}